// Round 1
// baseline (1846.444 us; speedup 1.0000x reference)
//
#include <hip/hip_runtime.h>
#include <cfloat>
#include <cmath>

#define SEP_ID 102
#define Bsz 64
#define Lseq 512
#define Hd 1024

// ---- workspace layout (float offsets) ----
#define OFF_COMBINED 0u          // 64*2048 = 131072
#define OFF_HBUF     131072u     // 64*2*1024 = 131072
#define OFF_GX       262144u     // 2*64*4096 = 524288
#define OFF_FLAGS    786432u     // 64*2*512 u32 = 65536 slots
#define OFF_WC       851968u     // 2*2048 = 4096
#define ZERO_BYTES   ((524288u + 65536u + 4096u) * 4u)   // Gx + flags + Wc

__device__ __forceinline__ float sigmoidf_(float x) {
  float t = __expf(-fabsf(x));
  float s = 1.0f / (1.0f + t);
  return x >= 0.f ? s : 1.f - s;
}
__device__ __forceinline__ float tanhf_(float x) {
  float t = __expf(-2.f * fabsf(x));
  float r = (1.f - t) / (1.f + t);
  return x >= 0.f ? r : -r;
}
__device__ __forceinline__ float dot4_(float4 a, float4 b) {
  return a.x * b.x + a.y * b.y + a.z * b.z + a.w * b.w;
}

// ============ K1: SEP find + segment max-pool -> combined[64][2048] ============
__global__ __launch_bounds__(256) void k_pool(const int* __restrict__ ids,
                                              const float* __restrict__ hs,
                                              float* __restrict__ ws) {
  int b = blockIdx.x >> 2;
  int quarter = blockIdx.x & 3;
  int tid = threadIdx.x;
  __shared__ int s0, s1, s2;
  if (tid == 0) { s0 = Lseq; s1 = Lseq; s2 = Lseq; }
  __syncthreads();
  int pA = tid, pB = tid + 256;
  int vA = ids[b * Lseq + pA], vB = ids[b * Lseq + pB];
  if (vA == SEP_ID) atomicMin(&s0, pA);
  if (vB == SEP_ID) atomicMin(&s0, pB);
  __syncthreads();
  if (vA == SEP_ID && pA > s0) atomicMin(&s1, pA);
  if (vB == SEP_ID && pB > s0) atomicMin(&s1, pB);
  __syncthreads();
  if (vA == SEP_ID && pA > s1) atomicMin(&s2, pA);
  if (vB == SEP_ID && pB > s1) atomicMin(&s2, pB);
  __syncthreads();
  int e1 = s1, e2 = s2;

  int gq = tid & 63, tp = tid >> 6;
  int c4 = quarter * 64 + gq;                 // float4 index within H (0..255)
  const float4* hp = (const float4*)(hs + (size_t)b * Lseq * Hd);
  float4 m1 = make_float4(-FLT_MAX, -FLT_MAX, -FLT_MAX, -FLT_MAX);
  float4 m2 = m1;
  for (int t = 1 + tp; t < e2; t += 4) {
    float4 v = hp[(size_t)t * 256 + c4];
    if (t < e1) {
      m1.x = fmaxf(m1.x, v.x); m1.y = fmaxf(m1.y, v.y);
      m1.z = fmaxf(m1.z, v.z); m1.w = fmaxf(m1.w, v.w);
    } else {
      m2.x = fmaxf(m2.x, v.x); m2.y = fmaxf(m2.y, v.y);
      m2.z = fmaxf(m2.z, v.z); m2.w = fmaxf(m2.w, v.w);
    }
  }
  __shared__ float4 r1s[256];
  __shared__ float4 r2s[256];
  r1s[tid] = m1; r2s[tid] = m2;
  __syncthreads();
  if (tp == 0) {
    float4 a = r1s[tid], bb = r1s[tid + 64], c = r1s[tid + 128], d = r1s[tid + 192];
    float4 o1;
    o1.x = fmaxf(fmaxf(a.x, bb.x), fmaxf(c.x, d.x));
    o1.y = fmaxf(fmaxf(a.y, bb.y), fmaxf(c.y, d.y));
    o1.z = fmaxf(fmaxf(a.z, bb.z), fmaxf(c.z, d.z));
    o1.w = fmaxf(fmaxf(a.w, bb.w), fmaxf(c.w, d.w));
    a = r2s[tid]; bb = r2s[tid + 64]; c = r2s[tid + 128]; d = r2s[tid + 192];
    float4 o2;
    o2.x = fmaxf(fmaxf(a.x, bb.x), fmaxf(c.x, d.x));
    o2.y = fmaxf(fmaxf(a.y, bb.y), fmaxf(c.y, d.y));
    o2.z = fmaxf(fmaxf(a.z, bb.z), fmaxf(c.z, d.z));
    o2.w = fmaxf(fmaxf(a.w, bb.w), fmaxf(c.w, d.w));
    float4* cw = (float4*)(ws + OFF_COMBINED + (size_t)b * 2048);
    cw[c4] = o1;          // s1 pool -> channels [0,1024)
    cw[256 + c4] = o2;    // s2 pool -> channels [1024,2048)
  }
}

// ============ K2: Gx[d][t][4096] += combined[t] @ w_ih_d^T (bias added in K3) ============
// grid 256 = dir(2) x jt(32, 128 j each) x kq(4, 512 k each); block 256
__global__ __launch_bounds__(256) void k_xgemm(const float* __restrict__ wih_f,
                                               const float* __restrict__ wih_b,
                                               float* __restrict__ ws) {
  int bid = blockIdx.x;
  int dir = bid >> 7;
  int jt  = (bid >> 2) & 31;
  int kq  = bid & 3;
  const float* wih = dir ? wih_b : wih_f;
  const float* comb = ws + OFF_COMBINED;
  float* gx = ws + OFF_GX + (size_t)dir * 64 * 4096;
  int jbase = jt * 128;
  int tid = threadIdx.x;
  int jg = tid & 31, tg = tid >> 5;

  __shared__ float wl[128][68];   // stride 68 floats = 17 float4 (odd -> 4-way max)
  __shared__ float cl[64][68];

  float acc[4][8] = {};

  for (int kk = 0; kk < 8; ++kk) {            // 8 chunks of 64 k
    int kab = kq * 512 + kk * 64;
    // stage w: 128 j x 64 k = 2048 float4, 8 per thread
#pragma unroll
    for (int r = 0; r < 8; ++r) {
      int f4 = r * 256 + tid;
      int jl = f4 >> 4, k4 = f4 & 15;
      float4 v = *(const float4*)&wih[(size_t)(jbase + jl) * 2048 + kab + k4 * 4];
      *(float4*)&wl[jl][k4 * 4] = v;
    }
    // stage c: 64 t x 64 k = 1024 float4, 4 per thread
#pragma unroll
    for (int r = 0; r < 4; ++r) {
      int f4 = r * 256 + tid;
      int tl = f4 >> 4, k4 = f4 & 15;
      float4 v = *(const float4*)&comb[(size_t)tl * 2048 + kab + k4 * 4];
      *(float4*)&cl[tl][k4 * 4] = v;
    }
    __syncthreads();
#pragma unroll
    for (int k4 = 0; k4 < 16; ++k4) {
      float4 wv[4], cv[8];
#pragma unroll
      for (int c = 0; c < 4; ++c) wv[c] = *(const float4*)&wl[jg + 32 * c][k4 * 4];
#pragma unroll
      for (int u = 0; u < 8; ++u) cv[u] = *(const float4*)&cl[tg * 8 + u][k4 * 4];
#pragma unroll
      for (int c = 0; c < 4; ++c)
#pragma unroll
        for (int u = 0; u < 8; ++u) acc[c][u] += dot4_(wv[c], cv[u]);
    }
    __syncthreads();
  }
#pragma unroll
  for (int c = 0; c < 4; ++c)
#pragma unroll
    for (int u = 0; u < 8; ++u)
      atomicAdd(&gx[(size_t)(tg * 8 + u) * 4096 + jbase + jg + 32 * c], acc[c][u]);
}

// ============ K4a: Wc[2][2048] = w2 @ w1 (f32 atomics into zeroed Wc) ============
__global__ __launch_bounds__(256) void k_wc(const float* __restrict__ w1,
                                            const float* __restrict__ w2,
                                            float* __restrict__ ws) {
  int j0 = blockIdx.x * 8;
  int tid = threadIdx.x;
  float* wc = ws + OFF_WC;
#pragma unroll
  for (int e = 0; e < 8; ++e) {
    int k = tid + e * 256;
    float a0 = 0.f, a1 = 0.f;
#pragma unroll
    for (int jj = 0; jj < 8; ++jj) {
      float v = w1[(size_t)(j0 + jj) * 2048 + k];
      a0 += w2[j0 + jj] * v;
      a1 += w2[2048 + j0 + jj] * v;
    }
    atomicAdd(&wc[k], a0);
    atomicAdd(&wc[2048 + k], a1);
  }
}

// ============ K3: persistent register-resident bidirectional LSTM ============
// grid 256 wg x 256 thr. dir = wg>>7; each wave owns 2 h-elements (all 4 gates).
__global__ __launch_bounds__(256, 2) void k_lstm(const float* __restrict__ whh_f,
                                                 const float* __restrict__ whh_b,
                                                 const float* __restrict__ bih_f,
                                                 const float* __restrict__ bhh_f,
                                                 const float* __restrict__ bih_b,
                                                 const float* __restrict__ bhh_b,
                                                 float* __restrict__ ws) {
  int wg = blockIdx.x;
  int dir = wg >> 7;
  int wgd = wg & 127;
  int tid = threadIdx.x;
  int wave = tid >> 6, lane = tid & 63;
  int m0 = wgd * 8 + wave * 2;
  const float* whh = dir ? whh_b : whh_f;
  const float* bih = dir ? bih_b : bih_f;
  const float* bhh = dir ? bhh_b : bhh_f;
  const float* gx = ws + OFF_GX + (size_t)dir * 64 * 4096;
  float* hbuf = ws + OFF_HBUF;
  unsigned int* flags = (unsigned int*)(ws + OFF_FLAGS);

  // register-resident w_hh fragment: wr[gate][mm][j], k = j*64 + lane
  float wr[4][2][16];
  float bias[4][2];
#pragma unroll
  for (int g = 0; g < 4; ++g)
#pragma unroll
    for (int mm = 0; mm < 2; ++mm) {
      const float* row = whh + (size_t)(g * 1024 + m0 + mm) * 1024;
#pragma unroll
      for (int j = 0; j < 16; ++j) wr[g][mm][j] = row[j * 64 + lane];
      bias[g][mm] = bih[g * 1024 + m0 + mm] + bhh[g * 1024 + m0 + mm];
    }

  float cst[2] = {0.f, 0.f};
  int wave_global = wgd * 4 + wave;   // 0..511 within direction

  for (int t = 0; t < 64; ++t) {
    float acc[4][2] = {};
    if (t > 0) {
      const unsigned long long* fl =
          (const unsigned long long*)(flags + ((size_t)(t - 1) * 2 + dir) * 512);
      const unsigned long long P = 0x0000000100000001ULL;
      int guard = 0;
      while (true) {
        unsigned long long f0 = __hip_atomic_load(fl + lane * 4 + 0, __ATOMIC_RELAXED, __HIP_MEMORY_SCOPE_AGENT);
        unsigned long long f1 = __hip_atomic_load(fl + lane * 4 + 1, __ATOMIC_RELAXED, __HIP_MEMORY_SCOPE_AGENT);
        unsigned long long f2 = __hip_atomic_load(fl + lane * 4 + 2, __ATOMIC_RELAXED, __HIP_MEMORY_SCOPE_AGENT);
        unsigned long long f3 = __hip_atomic_load(fl + lane * 4 + 3, __ATOMIC_RELAXED, __HIP_MEMORY_SCOPE_AGENT);
        int ok = (f0 == P) && (f1 == P) && (f2 == P) && (f3 == P);
        if (__all(ok)) break;
        if (++guard > 20000000) break;            // safety escape (no hang)
        __builtin_amdgcn_s_sleep(1);
      }
      __builtin_amdgcn_fence(__ATOMIC_ACQUIRE, "agent");
      const float* hprev = hbuf + ((size_t)(t - 1) * 2 + dir) * 1024;
#pragma unroll
      for (int j = 0; j < 16; ++j) {
        float hv = __hip_atomic_load(hprev + j * 64 + lane, __ATOMIC_RELAXED, __HIP_MEMORY_SCOPE_AGENT);
#pragma unroll
        for (int g = 0; g < 4; ++g) {
          acc[g][0] += wr[g][0][j] * hv;
          acc[g][1] += wr[g][1][j] * hv;
        }
      }
      // 64-lane butterfly reduce for all 8 partial dots
#pragma unroll
      for (int off = 32; off > 0; off >>= 1) {
#pragma unroll
        for (int g = 0; g < 4; ++g) {
          acc[g][0] += __shfl_xor(acc[g][0], off, 64);
          acc[g][1] += __shfl_xor(acc[g][1], off, 64);
        }
      }
    }
    int ts = dir ? (63 - t) : t;
    const float* gxt = gx + (size_t)ts * 4096;
    float hnew[2];
#pragma unroll
    for (int mm = 0; mm < 2; ++mm) {
      int m = m0 + mm;
      float gi = acc[0][mm] + gxt[m] + bias[0][mm];
      float gf = acc[1][mm] + gxt[1024 + m] + bias[1][mm];
      float gg = acc[2][mm] + gxt[2048 + m] + bias[2][mm];
      float go = acc[3][mm] + gxt[3072 + m] + bias[3][mm];
      cst[mm] = sigmoidf_(gf) * cst[mm] + sigmoidf_(gi) * tanhf_(gg);
      hnew[mm] = sigmoidf_(go) * tanhf_(cst[mm]);
    }
    float* hw = hbuf + ((size_t)t * 2 + dir) * 1024;
    if (lane == 0) {
      __hip_atomic_store(hw + m0, hnew[0], __ATOMIC_RELAXED, __HIP_MEMORY_SCOPE_AGENT);
      __hip_atomic_store(hw + m0 + 1, hnew[1], __ATOMIC_RELAXED, __HIP_MEMORY_SCOPE_AGENT);
      __builtin_amdgcn_fence(__ATOMIC_RELEASE, "agent");
      __hip_atomic_store(flags + ((size_t)t * 2 + dir) * 512 + wave_global, 1u,
                         __ATOMIC_RELAXED, __HIP_MEMORY_SCOPE_AGENT);
    }
  }
}

// ============ K4b: logits[64][2] = lstm_out @ Wc^T + (b2 + w2@b1) ============
__global__ __launch_bounds__(256) void k_logits(const float* __restrict__ w2,
                                                const float* __restrict__ b1,
                                                const float* __restrict__ b2,
                                                const float* __restrict__ ws,
                                                float* __restrict__ out) {
  int ts = blockIdx.x;
  int tid = threadIdx.x;
  const float* wc = ws + OFF_WC;
  const float* hbuf = ws + OFF_HBUF;
  float a0 = 0.f, a1 = 0.f;
#pragma unroll
  for (int e = 0; e < 2; ++e) {
    int k = tid * 8 + e * 4;
    float4 lv;
    if (k < 1024) lv = *(const float4*)&hbuf[((size_t)ts * 2 + 0) * 1024 + k];
    else          lv = *(const float4*)&hbuf[((size_t)(63 - ts) * 2 + 1) * 1024 + (k - 1024)];
    float4 w0 = *(const float4*)&wc[k];
    float4 w1v = *(const float4*)&wc[2048 + k];
    a0 += dot4_(lv, w0);
    a1 += dot4_(lv, w1v);
  }
  // folded bias: b2[r] + sum_j w2[r][j]*b1[j]
#pragma unroll
  for (int e = 0; e < 2; ++e) {
    int j = tid * 8 + e * 4;
    float4 bv = *(const float4*)&b1[j];
    float4 w0 = *(const float4*)&w2[j];
    float4 w1v = *(const float4*)&w2[2048 + j];
    a0 += dot4_(bv, w0);
    a1 += dot4_(bv, w1v);
  }
#pragma unroll
  for (int off = 32; off > 0; off >>= 1) {
    a0 += __shfl_xor(a0, off, 64);
    a1 += __shfl_xor(a1, off, 64);
  }
  __shared__ float red[2][4];
  int wave = tid >> 6, lane = tid & 63;
  if (lane == 0) { red[0][wave] = a0; red[1][wave] = a1; }
  __syncthreads();
  if (tid == 0) {
    out[ts * 2 + 0] = red[0][0] + red[0][1] + red[0][2] + red[0][3] + b2[0];
    out[ts * 2 + 1] = red[1][0] + red[1][1] + red[1][2] + red[1][3] + b2[1];
  }
}

extern "C" void kernel_launch(void* const* d_in, const int* in_sizes, int n_in,
                              void* d_out, int out_size, void* d_ws, size_t ws_size,
                              hipStream_t stream) {
  const int*   ids   = (const int*)d_in[0];
  const float* hs    = (const float*)d_in[1];
  const float* wih_f = (const float*)d_in[2];
  const float* whh_f = (const float*)d_in[3];
  const float* bih_f = (const float*)d_in[4];
  const float* bhh_f = (const float*)d_in[5];
  const float* wih_b = (const float*)d_in[6];
  const float* whh_b = (const float*)d_in[7];
  const float* bih_b = (const float*)d_in[8];
  const float* bhh_b = (const float*)d_in[9];
  const float* w1    = (const float*)d_in[10];
  const float* b1    = (const float*)d_in[11];
  const float* w2    = (const float*)d_in[12];
  const float* b2    = (const float*)d_in[13];
  float* ws = (float*)d_ws;
  float* out = (float*)d_out;

  // zero Gx + flags + Wc (graph-capturable; re-zeroed on every replay)
  hipMemsetAsync(ws + OFF_GX, 0, ZERO_BYTES, stream);

  k_pool  <<<dim3(256), dim3(256), 0, stream>>>(ids, hs, ws);
  k_xgemm <<<dim3(256), dim3(256), 0, stream>>>(wih_f, wih_b, ws);
  k_wc    <<<dim3(256), dim3(256), 0, stream>>>(w1, w2, ws);
  k_lstm  <<<dim3(256), dim3(256), 0, stream>>>(whh_f, whh_b, bih_f, bhh_f, bih_b, bhh_b, ws);
  k_logits<<<dim3(64),  dim3(256), 0, stream>>>(w2, b1, b2, ws, out);
}

// Round 2
// 469.665 us; speedup vs baseline: 3.9314x; 3.9314x over previous
//
#include <hip/hip_runtime.h>
#include <cfloat>
#include <cmath>

#define SEP_ID 102
#define Bsz 64
#define Lseq 512
#define Hd 1024

typedef unsigned long long u64;

// ---- workspace layout (float offsets) ----
#define OFF_COMBINED 0u          // 64*2048 = 131072 floats
#define OFF_GX       131072u     // 2*64*4096 = 524288 floats
#define OFF_WC       655360u     // 2*2048 = 4096 floats
#define OFF_HBUF     659456u     // u64[64][2][1024] = 131072 u64 = 262144 floats
#define ZERO_BYTES   ((524288u + 4096u + 262144u) * 4u)   // Gx + Wc + Hbuf(tags)

__device__ __forceinline__ float sigmoidf_(float x) {
  float t = __expf(-fabsf(x));
  float s = 1.0f / (1.0f + t);
  return x >= 0.f ? s : 1.f - s;
}
__device__ __forceinline__ float tanhf_(float x) {
  float t = __expf(-2.f * fabsf(x));
  float r = (1.f - t) / (1.f + t);
  return x >= 0.f ? r : -r;
}
__device__ __forceinline__ float dot4_(float4 a, float4 b) {
  return a.x * b.x + a.y * b.y + a.z * b.z + a.w * b.w;
}

// ============ K1: SEP find + segment max-pool -> combined[64][2048] ============
__global__ __launch_bounds__(256) void k_pool(const int* __restrict__ ids,
                                              const float* __restrict__ hs,
                                              float* __restrict__ ws) {
  int b = blockIdx.x >> 2;
  int quarter = blockIdx.x & 3;
  int tid = threadIdx.x;
  __shared__ int s0, s1, s2;
  if (tid == 0) { s0 = Lseq; s1 = Lseq; s2 = Lseq; }
  __syncthreads();
  int pA = tid, pB = tid + 256;
  int vA = ids[b * Lseq + pA], vB = ids[b * Lseq + pB];
  if (vA == SEP_ID) atomicMin(&s0, pA);
  if (vB == SEP_ID) atomicMin(&s0, pB);
  __syncthreads();
  if (vA == SEP_ID && pA > s0) atomicMin(&s1, pA);
  if (vB == SEP_ID && pB > s0) atomicMin(&s1, pB);
  __syncthreads();
  if (vA == SEP_ID && pA > s1) atomicMin(&s2, pA);
  if (vB == SEP_ID && pB > s1) atomicMin(&s2, pB);
  __syncthreads();
  int e1 = s1, e2 = s2;

  int gq = tid & 63, tp = tid >> 6;
  int c4 = quarter * 64 + gq;                 // float4 index within H (0..255)
  const float4* hp = (const float4*)(hs + (size_t)b * Lseq * Hd);
  float4 m1 = make_float4(-FLT_MAX, -FLT_MAX, -FLT_MAX, -FLT_MAX);
  float4 m2 = m1;
  for (int t = 1 + tp; t < e2; t += 4) {
    float4 v = hp[(size_t)t * 256 + c4];
    if (t < e1) {
      m1.x = fmaxf(m1.x, v.x); m1.y = fmaxf(m1.y, v.y);
      m1.z = fmaxf(m1.z, v.z); m1.w = fmaxf(m1.w, v.w);
    } else {
      m2.x = fmaxf(m2.x, v.x); m2.y = fmaxf(m2.y, v.y);
      m2.z = fmaxf(m2.z, v.z); m2.w = fmaxf(m2.w, v.w);
    }
  }
  __shared__ float4 r1s[256];
  __shared__ float4 r2s[256];
  r1s[tid] = m1; r2s[tid] = m2;
  __syncthreads();
  if (tp == 0) {
    float4 a = r1s[tid], bb = r1s[tid + 64], c = r1s[tid + 128], d = r1s[tid + 192];
    float4 o1;
    o1.x = fmaxf(fmaxf(a.x, bb.x), fmaxf(c.x, d.x));
    o1.y = fmaxf(fmaxf(a.y, bb.y), fmaxf(c.y, d.y));
    o1.z = fmaxf(fmaxf(a.z, bb.z), fmaxf(c.z, d.z));
    o1.w = fmaxf(fmaxf(a.w, bb.w), fmaxf(c.w, d.w));
    a = r2s[tid]; bb = r2s[tid + 64]; c = r2s[tid + 128]; d = r2s[tid + 192];
    float4 o2;
    o2.x = fmaxf(fmaxf(a.x, bb.x), fmaxf(c.x, d.x));
    o2.y = fmaxf(fmaxf(a.y, bb.y), fmaxf(c.y, d.y));
    o2.z = fmaxf(fmaxf(a.z, bb.z), fmaxf(c.z, d.z));
    o2.w = fmaxf(fmaxf(a.w, bb.w), fmaxf(c.w, d.w));
    float4* cw = (float4*)(ws + OFF_COMBINED + (size_t)b * 2048);
    cw[c4] = o1;          // s1 pool -> channels [0,1024)
    cw[256 + c4] = o2;    // s2 pool -> channels [1024,2048)
  }
}

// ============ K2: Gx[d][t][4096] += combined[t] @ w_ih_d^T (bias added in K3) ============
// grid 256 = dir(2) x jt(32, 128 j each) x kq(4, 512 k each); block 256
__global__ __launch_bounds__(256) void k_xgemm(const float* __restrict__ wih_f,
                                               const float* __restrict__ wih_b,
                                               float* __restrict__ ws) {
  int bid = blockIdx.x;
  int dir = bid >> 7;
  int jt  = (bid >> 2) & 31;
  int kq  = bid & 3;
  const float* wih = dir ? wih_b : wih_f;
  const float* comb = ws + OFF_COMBINED;
  float* gx = ws + OFF_GX + (size_t)dir * 64 * 4096;
  int jbase = jt * 128;
  int tid = threadIdx.x;
  int jg = tid & 31, tg = tid >> 5;

  __shared__ float wl[128][68];   // stride 68 floats = 17 float4 (odd -> 4-way max)
  __shared__ float cl[64][68];

  float acc[4][8] = {};

  for (int kk = 0; kk < 8; ++kk) {            // 8 chunks of 64 k
    int kab = kq * 512 + kk * 64;
    // stage w: 128 j x 64 k = 2048 float4, 8 per thread
#pragma unroll
    for (int r = 0; r < 8; ++r) {
      int f4 = r * 256 + tid;
      int jl = f4 >> 4, k4 = f4 & 15;
      float4 v = *(const float4*)&wih[(size_t)(jbase + jl) * 2048 + kab + k4 * 4];
      *(float4*)&wl[jl][k4 * 4] = v;
    }
    // stage c: 64 t x 64 k = 1024 float4, 4 per thread
#pragma unroll
    for (int r = 0; r < 4; ++r) {
      int f4 = r * 256 + tid;
      int tl = f4 >> 4, k4 = f4 & 15;
      float4 v = *(const float4*)&comb[(size_t)tl * 2048 + kab + k4 * 4];
      *(float4*)&cl[tl][k4 * 4] = v;
    }
    __syncthreads();
#pragma unroll
    for (int k4 = 0; k4 < 16; ++k4) {
      float4 wv[4], cv[8];
#pragma unroll
      for (int c = 0; c < 4; ++c) wv[c] = *(const float4*)&wl[jg + 32 * c][k4 * 4];
#pragma unroll
      for (int u = 0; u < 8; ++u) cv[u] = *(const float4*)&cl[tg * 8 + u][k4 * 4];
#pragma unroll
      for (int c = 0; c < 4; ++c)
#pragma unroll
        for (int u = 0; u < 8; ++u) acc[c][u] += dot4_(wv[c], cv[u]);
    }
    __syncthreads();
  }
#pragma unroll
  for (int c = 0; c < 4; ++c)
#pragma unroll
    for (int u = 0; u < 8; ++u)
      atomicAdd(&gx[(size_t)(tg * 8 + u) * 4096 + jbase + jg + 32 * c], acc[c][u]);
}

// ============ K4a: Wc[2][2048] = w2 @ w1 (f32 atomics into zeroed Wc) ============
__global__ __launch_bounds__(256) void k_wc(const float* __restrict__ w1,
                                            const float* __restrict__ w2,
                                            float* __restrict__ ws) {
  int j0 = blockIdx.x * 8;
  int tid = threadIdx.x;
  float* wc = ws + OFF_WC;
#pragma unroll
  for (int e = 0; e < 8; ++e) {
    int k = tid + e * 256;
    float a0 = 0.f, a1 = 0.f;
#pragma unroll
    for (int jj = 0; jj < 8; ++jj) {
      float v = w1[(size_t)(j0 + jj) * 2048 + k];
      a0 += w2[j0 + jj] * v;
      a1 += w2[2048 + j0 + jj] * v;
    }
    atomicAdd(&wc[k], a0);
    atomicAdd(&wc[2048 + k], a1);
  }
}

// ============ K3: persistent register-resident bidirectional LSTM ============
// grid 256 wg x 256 thr. dir = wg>>7; each wave owns 2 h-elements (all 4 gates).
// Sync: NO fences. Each h element is a u64 {tag = t+1, f32 bits} written with
// one relaxed agent-scope atomic store (data+flag in one atomic word -> no
// ordering needed). Consumers cooperatively poll the 1024 tagged slots,
// stage unpacked h into LDS once per block.
__global__ __launch_bounds__(256, 2) void k_lstm(const float* __restrict__ whh_f,
                                                 const float* __restrict__ whh_b,
                                                 const float* __restrict__ bih_f,
                                                 const float* __restrict__ bhh_f,
                                                 const float* __restrict__ bih_b,
                                                 const float* __restrict__ bhh_b,
                                                 float* __restrict__ ws) {
  int wg = blockIdx.x;
  int dir = wg >> 7;
  int wgd = wg & 127;
  int tid = threadIdx.x;
  int wave = tid >> 6, lane = tid & 63;
  int m0 = wgd * 8 + wave * 2;
  const float* whh = dir ? whh_b : whh_f;
  const float* bih = dir ? bih_b : bih_f;
  const float* bhh = dir ? bhh_b : bhh_f;
  const float* gx = ws + OFF_GX + (size_t)dir * 64 * 4096;
  u64* hb = (u64*)(ws + OFF_HBUF);

  __shared__ float hsm[1024];

  // register-resident w_hh fragment: wr[gate][mm][j], k = j*64 + lane
  float wr[4][2][16];
  float bias[4][2];
#pragma unroll
  for (int g = 0; g < 4; ++g)
#pragma unroll
    for (int mm = 0; mm < 2; ++mm) {
      const float* row = whh + (size_t)(g * 1024 + m0 + mm) * 1024;
#pragma unroll
      for (int j = 0; j < 16; ++j) wr[g][mm][j] = row[j * 64 + lane];
      bias[g][mm] = bih[g * 1024 + m0 + mm] + bhh[g * 1024 + m0 + mm];
    }

  float cst[2] = {0.f, 0.f};

  for (int t = 0; t < 64; ++t) {
    float acc[4][2] = {};
    if (t > 0) {
      const u64* hp = hb + ((size_t)(t - 1) * 2 + dir) * 1024;
      u64 etag = (u64)t;   // slot for step t-1 carries tag (t-1)+1 = t
      u64 v0, v1, v2, v3;
      int guard = 0;
      for (;;) {
        v0 = __hip_atomic_load(hp + tid,       __ATOMIC_RELAXED, __HIP_MEMORY_SCOPE_AGENT);
        v1 = __hip_atomic_load(hp + tid + 256, __ATOMIC_RELAXED, __HIP_MEMORY_SCOPE_AGENT);
        v2 = __hip_atomic_load(hp + tid + 512, __ATOMIC_RELAXED, __HIP_MEMORY_SCOPE_AGENT);
        v3 = __hip_atomic_load(hp + tid + 768, __ATOMIC_RELAXED, __HIP_MEMORY_SCOPE_AGENT);
        int ok = ((v0 >> 32) == etag) & ((v1 >> 32) == etag) &
                 ((v2 >> 32) == etag) & ((v3 >> 32) == etag);
        if (__syncthreads_and(ok)) break;
        if (++guard > 200000) break;            // safety escape (no hang)
        __builtin_amdgcn_s_sleep(1);
      }
      hsm[tid]       = __uint_as_float((unsigned)v0);
      hsm[tid + 256] = __uint_as_float((unsigned)v1);
      hsm[tid + 512] = __uint_as_float((unsigned)v2);
      hsm[tid + 768] = __uint_as_float((unsigned)v3);
      __syncthreads();
#pragma unroll
      for (int j = 0; j < 16; ++j) {
        float hv = hsm[j * 64 + lane];
#pragma unroll
        for (int g = 0; g < 4; ++g) {
          acc[g][0] += wr[g][0][j] * hv;
          acc[g][1] += wr[g][1][j] * hv;
        }
      }
      // 64-lane butterfly reduce for all 8 partial dots
#pragma unroll
      for (int off = 32; off > 0; off >>= 1) {
#pragma unroll
        for (int g = 0; g < 4; ++g) {
          acc[g][0] += __shfl_xor(acc[g][0], off, 64);
          acc[g][1] += __shfl_xor(acc[g][1], off, 64);
        }
      }
    }
    int ts = dir ? (63 - t) : t;
    const float* gxt = gx + (size_t)ts * 4096;
    float hnew[2];
#pragma unroll
    for (int mm = 0; mm < 2; ++mm) {
      int m = m0 + mm;
      float gi = acc[0][mm] + gxt[m] + bias[0][mm];
      float gf = acc[1][mm] + gxt[1024 + m] + bias[1][mm];
      float gg = acc[2][mm] + gxt[2048 + m] + bias[2][mm];
      float go = acc[3][mm] + gxt[3072 + m] + bias[3][mm];
      cst[mm] = sigmoidf_(gf) * cst[mm] + sigmoidf_(gi) * tanhf_(gg);
      hnew[mm] = sigmoidf_(go) * tanhf_(cst[mm]);
    }
    if (lane == 0) {
      u64* hw = hb + ((size_t)t * 2 + dir) * 1024 + m0;
      u64 p0 = ((u64)(t + 1) << 32) | (u64)__float_as_uint(hnew[0]);
      u64 p1 = ((u64)(t + 1) << 32) | (u64)__float_as_uint(hnew[1]);
      __hip_atomic_store(hw,     p0, __ATOMIC_RELAXED, __HIP_MEMORY_SCOPE_AGENT);
      __hip_atomic_store(hw + 1, p1, __ATOMIC_RELAXED, __HIP_MEMORY_SCOPE_AGENT);
    }
  }
}

// ============ K4b: logits[64][2] = lstm_out @ Wc^T + (b2 + w2@b1) ============
__global__ __launch_bounds__(256) void k_logits(const float* __restrict__ w2,
                                                const float* __restrict__ b1,
                                                const float* __restrict__ b2,
                                                const float* __restrict__ ws,
                                                float* __restrict__ out) {
  int ts = blockIdx.x;
  int tid = threadIdx.x;
  const float* wc = ws + OFF_WC;
  const u64* hb = (const u64*)(ws + OFF_HBUF);
  const u64* h0 = hb + ((size_t)ts * 2 + 0) * 1024;          // forward, step ts
  const u64* h1 = hb + ((size_t)(63 - ts) * 2 + 1) * 1024;   // backward output for pos ts
  float a0 = 0.f, a1 = 0.f;
#pragma unroll
  for (int e = 0; e < 8; ++e) {
    int k = tid + e * 256;
    u64 v = (k < 1024) ? h0[k] : h1[k - 1024];
    float hv = __uint_as_float((unsigned)v);
    a0 += hv * wc[k];
    a1 += hv * wc[2048 + k];
  }
  // folded bias: b2[r] + sum_j w2[r][j]*b1[j]
#pragma unroll
  for (int e = 0; e < 8; ++e) {
    int j = tid + e * 256;
    float bv = b1[j];
    a0 += bv * w2[j];
    a1 += bv * w2[2048 + j];
  }
#pragma unroll
  for (int off = 32; off > 0; off >>= 1) {
    a0 += __shfl_xor(a0, off, 64);
    a1 += __shfl_xor(a1, off, 64);
  }
  __shared__ float red[2][4];
  int wave = tid >> 6, lane = tid & 63;
  if (lane == 0) { red[0][wave] = a0; red[1][wave] = a1; }
  __syncthreads();
  if (tid == 0) {
    out[ts * 2 + 0] = red[0][0] + red[0][1] + red[0][2] + red[0][3] + b2[0];
    out[ts * 2 + 1] = red[1][0] + red[1][1] + red[1][2] + red[1][3] + b2[1];
  }
}

extern "C" void kernel_launch(void* const* d_in, const int* in_sizes, int n_in,
                              void* d_out, int out_size, void* d_ws, size_t ws_size,
                              hipStream_t stream) {
  const int*   ids   = (const int*)d_in[0];
  const float* hs    = (const float*)d_in[1];
  const float* wih_f = (const float*)d_in[2];
  const float* whh_f = (const float*)d_in[3];
  const float* bih_f = (const float*)d_in[4];
  const float* bhh_f = (const float*)d_in[5];
  const float* wih_b = (const float*)d_in[6];
  const float* whh_b = (const float*)d_in[7];
  const float* bih_b = (const float*)d_in[8];
  const float* bhh_b = (const float*)d_in[9];
  const float* w1    = (const float*)d_in[10];
  const float* b1    = (const float*)d_in[11];
  const float* w2    = (const float*)d_in[12];
  const float* b2    = (const float*)d_in[13];
  float* ws = (float*)d_ws;
  float* out = (float*)d_out;

  // zero Gx + Wc + Hbuf tags (graph-capturable; re-zeroed on every replay)
  hipMemsetAsync(ws + OFF_GX, 0, ZERO_BYTES, stream);

  k_pool  <<<dim3(256), dim3(256), 0, stream>>>(ids, hs, ws);
  k_xgemm <<<dim3(256), dim3(256), 0, stream>>>(wih_f, wih_b, ws);
  k_wc    <<<dim3(256), dim3(256), 0, stream>>>(w1, w2, ws);
  k_lstm  <<<dim3(256), dim3(256), 0, stream>>>(whh_f, whh_b, bih_f, bhh_f, bih_b, bhh_b, ws);
  k_logits<<<dim3(64),  dim3(256), 0, stream>>>(w2, b1, b2, ws, out);
}

// Round 3
// 460.358 us; speedup vs baseline: 4.0109x; 1.0202x over previous
//
#include <hip/hip_runtime.h>
#include <cfloat>
#include <cmath>

#define SEP_ID 102
#define Bsz 64
#define Lseq 512
#define Hd 1024

typedef unsigned long long u64;

// ---- workspace layout (float offsets) ----
#define OFF_COMBINED 0u          // 64*2048 = 131072 floats
#define OFF_GX0      131072u     // 2*64*4096 = 524288 floats (K-half 0)
#define OFF_GX1      655360u     // 2*64*4096 = 524288 floats (K-half 1)
#define OFF_WC       1179648u    // 2*2048 = 4096 floats
#define OFF_HBUF     1183744u    // u64[64][2][1024] = 262144 floats
#define ZERO_BYTES   ((4096u + 262144u) * 4u)   // Wc + Hbuf(tags) only

__device__ __forceinline__ float sigmoidf_(float x) {
  float t = __expf(-fabsf(x));
  float s = 1.0f / (1.0f + t);
  return x >= 0.f ? s : 1.f - s;
}
__device__ __forceinline__ float tanhf_(float x) {
  float t = __expf(-2.f * fabsf(x));
  float r = (1.f - t) / (1.f + t);
  return x >= 0.f ? r : -r;
}
__device__ __forceinline__ float dot4_(float4 a, float4 b) {
  return a.x * b.x + a.y * b.y + a.z * b.z + a.w * b.w;
}

// ============ K1: SEP find + segment max-pool -> combined[64][2048] ============
__global__ __launch_bounds__(256) void k_pool(const int* __restrict__ ids,
                                              const float* __restrict__ hs,
                                              float* __restrict__ ws) {
  int b = blockIdx.x >> 2;
  int quarter = blockIdx.x & 3;
  int tid = threadIdx.x;
  __shared__ int s0, s1, s2;
  if (tid == 0) { s0 = Lseq; s1 = Lseq; s2 = Lseq; }
  __syncthreads();
  int pA = tid, pB = tid + 256;
  int vA = ids[b * Lseq + pA], vB = ids[b * Lseq + pB];
  if (vA == SEP_ID) atomicMin(&s0, pA);
  if (vB == SEP_ID) atomicMin(&s0, pB);
  __syncthreads();
  if (vA == SEP_ID && pA > s0) atomicMin(&s1, pA);
  if (vB == SEP_ID && pB > s0) atomicMin(&s1, pB);
  __syncthreads();
  if (vA == SEP_ID && pA > s1) atomicMin(&s2, pA);
  if (vB == SEP_ID && pB > s1) atomicMin(&s2, pB);
  __syncthreads();
  int e1 = s1, e2 = s2;

  int gq = tid & 63, tp = tid >> 6;
  int c4 = quarter * 64 + gq;                 // float4 index within H (0..255)
  const float4* hp = (const float4*)(hs + (size_t)b * Lseq * Hd);
  float4 m1 = make_float4(-FLT_MAX, -FLT_MAX, -FLT_MAX, -FLT_MAX);
  float4 m2 = m1;
  for (int t = 1 + tp; t < e2; t += 4) {
    float4 v = hp[(size_t)t * 256 + c4];
    if (t < e1) {
      m1.x = fmaxf(m1.x, v.x); m1.y = fmaxf(m1.y, v.y);
      m1.z = fmaxf(m1.z, v.z); m1.w = fmaxf(m1.w, v.w);
    } else {
      m2.x = fmaxf(m2.x, v.x); m2.y = fmaxf(m2.y, v.y);
      m2.z = fmaxf(m2.z, v.z); m2.w = fmaxf(m2.w, v.w);
    }
  }
  __shared__ float4 r1s[256];
  __shared__ float4 r2s[256];
  r1s[tid] = m1; r2s[tid] = m2;
  __syncthreads();
  if (tp == 0) {
    float4 a = r1s[tid], bb = r1s[tid + 64], c = r1s[tid + 128], d = r1s[tid + 192];
    float4 o1;
    o1.x = fmaxf(fmaxf(a.x, bb.x), fmaxf(c.x, d.x));
    o1.y = fmaxf(fmaxf(a.y, bb.y), fmaxf(c.y, d.y));
    o1.z = fmaxf(fmaxf(a.z, bb.z), fmaxf(c.z, d.z));
    o1.w = fmaxf(fmaxf(a.w, bb.w), fmaxf(c.w, d.w));
    a = r2s[tid]; bb = r2s[tid + 64]; c = r2s[tid + 128]; d = r2s[tid + 192];
    float4 o2;
    o2.x = fmaxf(fmaxf(a.x, bb.x), fmaxf(c.x, d.x));
    o2.y = fmaxf(fmaxf(a.y, bb.y), fmaxf(c.y, d.y));
    o2.z = fmaxf(fmaxf(a.z, bb.z), fmaxf(c.z, d.z));
    o2.w = fmaxf(fmaxf(a.w, bb.w), fmaxf(c.w, d.w));
    float4* cw = (float4*)(ws + OFF_COMBINED + (size_t)b * 2048);
    cw[c4] = o1;          // s1 pool -> channels [0,1024)
    cw[256 + c4] = o2;    // s2 pool -> channels [1024,2048)
  }
}

// ============ K2: Gx{0,1}[d][t][4096] = combined[t] @ w_ih_d^T (half-K each) ============
// grid 128 = dir(2) x jt(32, 128 j each) x kq(2, 1024 k each); block 256. Plain stores.
__global__ __launch_bounds__(256) void k_xgemm(const float* __restrict__ wih_f,
                                               const float* __restrict__ wih_b,
                                               float* __restrict__ ws) {
  int bid = blockIdx.x;
  int dir = bid >> 6;
  int jt  = (bid >> 1) & 31;
  int kq  = bid & 1;
  const float* wih = dir ? wih_b : wih_f;
  const float* comb = ws + OFF_COMBINED;
  float* gx = ws + (kq ? OFF_GX1 : OFF_GX0) + (size_t)dir * 64 * 4096;
  int jbase = jt * 128;
  int tid = threadIdx.x;
  int jg = tid & 31, tg = tid >> 5;

  __shared__ float wl[128][68];   // stride 68 floats = 17 float4 (odd -> 4-way max)
  __shared__ float cl[64][68];

  float acc[4][8] = {};

  for (int kk = 0; kk < 16; ++kk) {            // 16 chunks of 64 k
    int kab = kq * 1024 + kk * 64;
    // stage w: 128 j x 64 k = 2048 float4, 8 per thread
#pragma unroll
    for (int r = 0; r < 8; ++r) {
      int f4 = r * 256 + tid;
      int jl = f4 >> 4, k4 = f4 & 15;
      float4 v = *(const float4*)&wih[(size_t)(jbase + jl) * 2048 + kab + k4 * 4];
      *(float4*)&wl[jl][k4 * 4] = v;
    }
    // stage c: 64 t x 64 k = 1024 float4, 4 per thread
#pragma unroll
    for (int r = 0; r < 4; ++r) {
      int f4 = r * 256 + tid;
      int tl = f4 >> 4, k4 = f4 & 15;
      float4 v = *(const float4*)&comb[(size_t)tl * 2048 + kab + k4 * 4];
      *(float4*)&cl[tl][k4 * 4] = v;
    }
    __syncthreads();
#pragma unroll
    for (int k4 = 0; k4 < 16; ++k4) {
      float4 wv[4], cv[8];
#pragma unroll
      for (int c = 0; c < 4; ++c) wv[c] = *(const float4*)&wl[jg + 32 * c][k4 * 4];
#pragma unroll
      for (int u = 0; u < 8; ++u) cv[u] = *(const float4*)&cl[tg * 8 + u][k4 * 4];
#pragma unroll
      for (int c = 0; c < 4; ++c)
#pragma unroll
        for (int u = 0; u < 8; ++u) acc[c][u] += dot4_(wv[c], cv[u]);
    }
    __syncthreads();
  }
#pragma unroll
  for (int c = 0; c < 4; ++c)
#pragma unroll
    for (int u = 0; u < 8; ++u)
      gx[(size_t)(tg * 8 + u) * 4096 + jbase + jg + 32 * c] = acc[c][u];
}

// ============ K4a: Wc[2][2048] = w2 @ w1 (f32 atomics into zeroed Wc) ============
__global__ __launch_bounds__(256) void k_wc(const float* __restrict__ w1,
                                            const float* __restrict__ w2,
                                            float* __restrict__ ws) {
  int j0 = blockIdx.x * 8;
  int tid = threadIdx.x;
  float* wc = ws + OFF_WC;
#pragma unroll
  for (int e = 0; e < 8; ++e) {
    int k = tid + e * 256;
    float a0 = 0.f, a1 = 0.f;
#pragma unroll
    for (int jj = 0; jj < 8; ++jj) {
      float v = w1[(size_t)(j0 + jj) * 2048 + k];
      a0 += w2[j0 + jj] * v;
      a1 += w2[2048 + j0 + jj] * v;
    }
    atomicAdd(&wc[k], a0);
    atomicAdd(&wc[2048 + k], a1);
  }
}

// ============ K3: persistent register-resident bidirectional LSTM ============
// grid 256 wg x 256 thr. dir = wg>>7; each wave owns 2 h-elements (all 4 gates).
// h elements are tagged u64 {tag=t+1, f32} relaxed agent-scope atomics (no fences).
// Weights are PINNED into VGPRs via empty asm (prevents per-step remat/reload).
__global__ __launch_bounds__(256, 2) void k_lstm(const float* __restrict__ whh_f,
                                                 const float* __restrict__ whh_b,
                                                 const float* __restrict__ bih_f,
                                                 const float* __restrict__ bhh_f,
                                                 const float* __restrict__ bih_b,
                                                 const float* __restrict__ bhh_b,
                                                 float* __restrict__ ws) {
  int wg = blockIdx.x;
  int dir = wg >> 7;
  int wgd = wg & 127;
  int tid = threadIdx.x;
  int wave = tid >> 6, lane = tid & 63;
  int m0 = wgd * 8 + wave * 2;
  const float* whh = dir ? whh_b : whh_f;
  const float* bih = dir ? bih_b : bih_f;
  const float* bhh = dir ? bhh_b : bhh_f;
  const float* gx0 = ws + OFF_GX0 + (size_t)dir * 64 * 4096;
  const float* gx1 = ws + OFF_GX1 + (size_t)dir * 64 * 4096;
  u64* hb = (u64*)(ws + OFF_HBUF);

  __shared__ float hsm[1024];

  // register-resident w_hh fragment: wr[gate][mm][j], k = j*64 + lane
  float wr[4][2][16];
  float bias[4][2];
#pragma unroll
  for (int g = 0; g < 4; ++g)
#pragma unroll
    for (int mm = 0; mm < 2; ++mm) {
      const float* row = whh + (size_t)(g * 1024 + m0 + mm) * 1024;
#pragma unroll
      for (int j = 0; j < 16; ++j) wr[g][mm][j] = row[j * 64 + lane];
      bias[g][mm] = bih[g * 1024 + m0 + mm] + bhh[g * 1024 + m0 + mm];
    }
  // PIN: make every weight opaque to the compiler -> must stay in a VGPR,
  // cannot be rematerialized by reloading from global memory each step.
#pragma unroll
  for (int g = 0; g < 4; ++g)
#pragma unroll
    for (int mm = 0; mm < 2; ++mm)
#pragma unroll
      for (int j = 0; j < 16; ++j)
        asm volatile("" : "+v"(wr[g][mm][j]));

  float cst[2] = {0.f, 0.f};

  for (int t = 0; t < 64; ++t) {
    int ts = dir ? (63 - t) : t;
    const float* gxt0 = gx0 + (size_t)ts * 4096;
    const float* gxt1 = gx1 + (size_t)ts * 4096;
    // prefetch x-part gates + bias (overlaps the poll below)
    float gpre[4][2];
#pragma unroll
    for (int g = 0; g < 4; ++g)
#pragma unroll
      for (int mm = 0; mm < 2; ++mm)
        gpre[g][mm] = gxt0[g * 1024 + m0 + mm] + gxt1[g * 1024 + m0 + mm] + bias[g][mm];

    float acc[4][2] = {};
    if (t > 0) {
      const u64* hp = hb + ((size_t)(t - 1) * 2 + dir) * 1024;
      u64 etag = (u64)t;   // slot for step t-1 carries tag (t-1)+1 = t
      u64 v0 = 0, v1 = 0, v2 = 0, v3 = 0;
      int r0 = 0, r1 = 0, r2 = 0, r3 = 0;
      int guard = 0;
      for (;;) {
        if (!r0) { u64 x = __hip_atomic_load(hp + tid,       __ATOMIC_RELAXED, __HIP_MEMORY_SCOPE_AGENT); if ((x >> 32) == etag) { v0 = x; r0 = 1; } }
        if (!r1) { u64 x = __hip_atomic_load(hp + tid + 256, __ATOMIC_RELAXED, __HIP_MEMORY_SCOPE_AGENT); if ((x >> 32) == etag) { v1 = x; r1 = 1; } }
        if (!r2) { u64 x = __hip_atomic_load(hp + tid + 512, __ATOMIC_RELAXED, __HIP_MEMORY_SCOPE_AGENT); if ((x >> 32) == etag) { v2 = x; r2 = 1; } }
        if (!r3) { u64 x = __hip_atomic_load(hp + tid + 768, __ATOMIC_RELAXED, __HIP_MEMORY_SCOPE_AGENT); if ((x >> 32) == etag) { v3 = x; r3 = 1; } }
        if (r0 & r1 & r2 & r3) break;
        if (++guard > 300000) break;            // safety escape (no hang)
        __builtin_amdgcn_s_sleep(1);
      }
      hsm[tid]       = __uint_as_float((unsigned)v0);
      hsm[tid + 256] = __uint_as_float((unsigned)v1);
      hsm[tid + 512] = __uint_as_float((unsigned)v2);
      hsm[tid + 768] = __uint_as_float((unsigned)v3);
      __syncthreads();
#pragma unroll
      for (int j = 0; j < 16; ++j) {
        float hv = hsm[j * 64 + lane];
#pragma unroll
        for (int g = 0; g < 4; ++g) {
          acc[g][0] += wr[g][0][j] * hv;
          acc[g][1] += wr[g][1][j] * hv;
        }
      }
      // 64-lane butterfly reduce for all 8 partial dots
#pragma unroll
      for (int off = 32; off > 0; off >>= 1) {
#pragma unroll
        for (int g = 0; g < 4; ++g) {
          acc[g][0] += __shfl_xor(acc[g][0], off, 64);
          acc[g][1] += __shfl_xor(acc[g][1], off, 64);
        }
      }
    }
    float hnew[2];
#pragma unroll
    for (int mm = 0; mm < 2; ++mm) {
      float gi = acc[0][mm] + gpre[0][mm];
      float gf = acc[1][mm] + gpre[1][mm];
      float gg = acc[2][mm] + gpre[2][mm];
      float go = acc[3][mm] + gpre[3][mm];
      cst[mm] = sigmoidf_(gf) * cst[mm] + sigmoidf_(gi) * tanhf_(gg);
      hnew[mm] = sigmoidf_(go) * tanhf_(cst[mm]);
    }
    if (lane == 0) {
      u64* hw = hb + ((size_t)t * 2 + dir) * 1024 + m0;
      u64 p0 = ((u64)(t + 1) << 32) | (u64)__float_as_uint(hnew[0]);
      u64 p1 = ((u64)(t + 1) << 32) | (u64)__float_as_uint(hnew[1]);
      __hip_atomic_store(hw,     p0, __ATOMIC_RELAXED, __HIP_MEMORY_SCOPE_AGENT);
      __hip_atomic_store(hw + 1, p1, __ATOMIC_RELAXED, __HIP_MEMORY_SCOPE_AGENT);
    }
  }
}

// ============ K4b: logits[64][2] = lstm_out @ Wc^T + (b2 + w2@b1) ============
__global__ __launch_bounds__(256) void k_logits(const float* __restrict__ w2,
                                                const float* __restrict__ b1,
                                                const float* __restrict__ b2,
                                                const float* __restrict__ ws,
                                                float* __restrict__ out) {
  int ts = blockIdx.x;
  int tid = threadIdx.x;
  const float* wc = ws + OFF_WC;
  const u64* hb = (const u64*)(ws + OFF_HBUF);
  const u64* h0 = hb + ((size_t)ts * 2 + 0) * 1024;          // forward, step ts
  const u64* h1 = hb + ((size_t)(63 - ts) * 2 + 1) * 1024;   // backward output for pos ts
  float a0 = 0.f, a1 = 0.f;
#pragma unroll
  for (int e = 0; e < 8; ++e) {
    int k = tid + e * 256;
    u64 v = (k < 1024) ? h0[k] : h1[k - 1024];
    float hv = __uint_as_float((unsigned)v);
    a0 += hv * wc[k];
    a1 += hv * wc[2048 + k];
  }
  // folded bias: b2[r] + sum_j w2[r][j]*b1[j]
#pragma unroll
  for (int e = 0; e < 8; ++e) {
    int j = tid + e * 256;
    float bv = b1[j];
    a0 += bv * w2[j];
    a1 += bv * w2[2048 + j];
  }
#pragma unroll
  for (int off = 32; off > 0; off >>= 1) {
    a0 += __shfl_xor(a0, off, 64);
    a1 += __shfl_xor(a1, off, 64);
  }
  __shared__ float red[2][4];
  int wave = tid >> 6, lane = tid & 63;
  if (lane == 0) { red[0][wave] = a0; red[1][wave] = a1; }
  __syncthreads();
  if (tid == 0) {
    out[ts * 2 + 0] = red[0][0] + red[0][1] + red[0][2] + red[0][3] + b2[0];
    out[ts * 2 + 1] = red[1][0] + red[1][1] + red[1][2] + red[1][3] + b2[1];
  }
}

extern "C" void kernel_launch(void* const* d_in, const int* in_sizes, int n_in,
                              void* d_out, int out_size, void* d_ws, size_t ws_size,
                              hipStream_t stream) {
  const int*   ids   = (const int*)d_in[0];
  const float* hs    = (const float*)d_in[1];
  const float* wih_f = (const float*)d_in[2];
  const float* whh_f = (const float*)d_in[3];
  const float* bih_f = (const float*)d_in[4];
  const float* bhh_f = (const float*)d_in[5];
  const float* wih_b = (const float*)d_in[6];
  const float* whh_b = (const float*)d_in[7];
  const float* bih_b = (const float*)d_in[8];
  const float* bhh_b = (const float*)d_in[9];
  const float* w1    = (const float*)d_in[10];
  const float* b1    = (const float*)d_in[11];
  const float* w2    = (const float*)d_in[12];
  const float* b2    = (const float*)d_in[13];
  float* ws = (float*)d_ws;
  float* out = (float*)d_out;

  // zero Wc + Hbuf tags (graph-capturable; re-zeroed on every replay)
  hipMemsetAsync(ws + OFF_WC, 0, ZERO_BYTES, stream);

  k_pool  <<<dim3(256), dim3(256), 0, stream>>>(ids, hs, ws);
  k_xgemm <<<dim3(128), dim3(256), 0, stream>>>(wih_f, wih_b, ws);
  k_wc    <<<dim3(256), dim3(256), 0, stream>>>(w1, w2, ws);
  k_lstm  <<<dim3(256), dim3(256), 0, stream>>>(whh_f, whh_b, bih_f, bhh_f, bih_b, bhh_b, ws);
  k_logits<<<dim3(64),  dim3(256), 0, stream>>>(w2, b1, b2, ws, out);
}